// Round 14
// baseline (282.540 us; speedup 1.0000x reference)
//
#include <hip/hip_runtime.h>
#include <stdint.h>

typedef __attribute__((ext_vector_type(8))) short bf16x8;
typedef __attribute__((ext_vector_type(4))) float f32x4;

__device__ __forceinline__ unsigned short f2bf(float f) {
  union { float f; unsigned u; } v; v.f = f;
  unsigned r = v.u + 0x7FFFu + ((v.u >> 16) & 1u);
  return (unsigned short)(r >> 16);
}

// fast sigmoid: v_rcp_f32 (1 inst) instead of IEEE div sequence (~9 inst).
__device__ __forceinline__ float sigm(float x) {
  return __builtin_amdgcn_rcpf(1.0f + __expf(-x));
}

__device__ __forceinline__ unsigned cvtpk(float lo, float hi) {
  unsigned u;
  asm("v_cvt_pk_bf16_f32 %0, %1, %2" : "=v"(u) : "v"(lo), "v"(hi));
  return u;
}

__device__ __forceinline__ void gload16(const void* g, void* l) {
  __builtin_amdgcn_global_load_lds((const __attribute__((address_space(1))) void*)g,
                                   (__attribute__((address_space(3))) void*)l, 16, 0, 0);
}

__device__ __forceinline__ void bar() {
  __builtin_amdgcn_sched_barrier(0);
  __builtin_amdgcn_s_barrier();
  __builtin_amdgcn_sched_barrier(0);
}

// ---------------- K0T: cheb fp32 -> bf16 (normal + transposed), one pass ----------------
__global__ void k0t(const float* __restrict__ cheb, unsigned short* __restrict__ cb1,
                    unsigned short* __restrict__ cb2, unsigned short* __restrict__ Pbig,
                    unsigned short* __restrict__ t0, unsigned short* __restrict__ t1) {
  __shared__ unsigned short t[64][65];
  const int z = blockIdx.z;
  const int c = threadIdx.x & 63, r4 = threadIdx.x >> 6;
  const int r0 = blockIdx.y * 64, c0 = blockIdx.x * 64;
  const float* src = cheb + (size_t)z * 1048576;
#pragma unroll
  for (int r = 0; r < 64; r += 4) {
    const int rr = r0 + r + r4;
    const unsigned short h = f2bf(src[(size_t)rr * 1024 + c0 + c]);
    t[r + r4][c] = h;
    if (z == 0) Pbig[(size_t)rr * 3072 + c0 + c] = h;
    else if (z == 1) cb1[(size_t)rr * 1024 + c0 + c] = h;
    else cb2[(size_t)rr * 1024 + c0 + c] = h;
  }
  __syncthreads();
  if (z == 2) return;
  unsigned short* dst = z ? t1 : t0;
#pragma unroll
  for (int r = 0; r < 64; r += 4)
    dst[(size_t)(c0 + r + r4) * 1024 + r0 + c] = t[c][r + r4];
}

// ---------------- gemm_splitk: 128^2 tile, K=1024 split into 2 chunks of 512 ----------------
__global__ __launch_bounds__(256) void gemm_splitk(
    const unsigned short* __restrict__ A1, const unsigned short* __restrict__ B1,
    float* __restrict__ C1,
    const unsigned short* __restrict__ A2, const unsigned short* __restrict__ B2,
    float* __restrict__ C2) {
  __shared__ __align__(16) unsigned short sA[128 * 32];
  __shared__ __align__(16) unsigned short sB[128 * 32];
  const unsigned short* Ap = blockIdx.z ? A2 : A1;
  const unsigned short* Bp = blockIdx.z ? B2 : B1;
  float* Cp = blockIdx.z ? C2 : C1;
  const int mb = blockIdx.x & 7, nb = blockIdx.x >> 3, ks = blockIdx.y;
  const int tid = threadIdx.x;
  const int lane = tid & 63;
  const int w = tid >> 6;
  const int m0 = mb * 128, n0 = nb * 128;
  const int wm = (w >> 1) * 64, wn = (w & 1) * 64;
  const int lr = lane & 15, lg = lane >> 4;
  const f32x4 ZV = {0.f, 0.f, 0.f, 0.f};
  f32x4 acc[4][4];
#pragma unroll
  for (int f = 0; f < 4; ++f)
#pragma unroll
    for (int g = 0; g < 4; ++g) acc[f][g] = ZV;
  const int r2 = tid >> 2, kp = tid & 3;
  const size_t rowA0 = (size_t)(m0 + r2) * 1024;
  const size_t rowA1 = (size_t)(m0 + 64 + r2) * 1024;
  const size_t rowB0 = (size_t)(n0 + r2) * 1024;
  const size_t rowB1 = (size_t)(n0 + 64 + r2) * 1024;
  unsigned short* la = &sA[w * 512];
  unsigned short* lb = &sB[w * 512];
  const int kbase = ks * 512;
  for (int k0 = kbase; k0 < kbase + 512; k0 += 32) {
    const int kc = k0 + kp * 8;
    gload16(Ap + rowA0 + kc, la);
    gload16(Ap + rowA1 + kc, la + 2048);
    gload16(Bp + rowB0 + kc, lb);
    gload16(Bp + rowB1 + kc, lb + 2048);
    __syncthreads();
    bf16x8 av[4], bv[4];
#pragma unroll
    for (int f = 0; f < 4; ++f)
      av[f] = *(const bf16x8*)&sA[(wm + f * 16 + lr) * 32 + lg * 8];
#pragma unroll
    for (int g = 0; g < 4; ++g)
      bv[g] = *(const bf16x8*)&sB[(wn + g * 16 + lr) * 32 + lg * 8];
#pragma unroll
    for (int f = 0; f < 4; ++f)
#pragma unroll
      for (int g = 0; g < 4; ++g)
        acc[f][g] = __builtin_amdgcn_mfma_f32_16x16x32_bf16(av[f], bv[g], acc[f][g], 0, 0, 0);
    __syncthreads();
  }
  float* Cb = Cp + (size_t)ks * 1048576;
#pragma unroll
  for (int f = 0; f < 4; ++f) {
    const int m = m0 + wm + f * 16 + lg * 4;
#pragma unroll
    for (int g = 0; g < 4; ++g) {
      const int col = n0 + wn + g * 16 + lr;
#pragma unroll
      for (int i = 0; i < 4; ++i)
        Cb[(size_t)(m + i) * 1024 + col] = acc[f][g][i];
    }
  }
}

// ---------------- reducep: sum 2 fp32 split-partials -> bf16 dst (deterministic) ----------------
__global__ void reducep(const float* __restrict__ S1, unsigned short* __restrict__ D1, int ld1, int co1,
                        const float* __restrict__ S2, unsigned short* __restrict__ D2, int ld2, int co2) {
  const float* S = blockIdx.z ? S2 : S1;
  unsigned short* D = blockIdx.z ? D2 : D1;
  const int ld = blockIdx.z ? ld2 : ld1;
  const int co = blockIdx.z ? co2 : co1;
  const int e = (blockIdx.x * 256 + threadIdx.x) * 4;
  const float4 a = *(const float4*)&S[e];
  const float4 b = *(const float4*)&S[1048576 + e];
  const int row = e >> 10, col = e & 1023;
  ushort4 o;
  o.x = f2bf(a.x + b.x);
  o.y = f2bf(a.y + b.y);
  o.z = f2bf(a.z + b.z);
  o.w = f2bf(a.w + b.w);
  *(ushort4*)&D[(size_t)row * ld + co + col] = o;
}

// ---------------- gemm_big: 256x256 tile, BK=32, depth-4 LDS, reg dbuf, 1 bar/tile ----------------
// (round-6 proven version, verbatim — ~105 us)
__device__ __forceinline__ void dec_chunk(int s, int& row, int& c) {
  const int r3 = (((s >> 2) ^ (s >> 4)) & 1) | (((s >> 3) & 1) << 1) | (((s >> 4) & 1) << 2);
  const int u = s ^ r3;
  row = u >> 2;
  c = u & 3;
}

__global__ __launch_bounds__(512, 2) void gemm_big(
    const unsigned short* __restrict__ A, const unsigned short* __restrict__ Bt,
    unsigned short* __restrict__ C) {
  constexpr int K = 3072, NT = 96;  // NT = K/32
  __shared__ __align__(16) unsigned short lds[4 * 16384];  // 128 KiB: 4 bufs x [A 16KB | B 16KB]
  const int tid = threadIdx.x;
  const int lane = tid & 63, w = tid >> 6;
  const int wr = w >> 2, wc = w & 3;
  const int lr = lane & 15, lg = lane >> 4;
  const int lin = blockIdx.x;                 // 248 blocks: XCD-bijective swizzle (248 = 8*31)
  const int v = (lin & 7) * 31 + (lin >> 3);
  const int mb = v & 3, nb = v >> 2;
  const int m0 = mb * 256, n0 = nb * 256;

  int r0_, c0_, r1_, c1_;
  dec_chunk((w * 2 + 0) * 64 + lane, r0_, c0_);
  dec_chunk((w * 2 + 1) * 64 + lane, r1_, c1_);
  const unsigned short* sA0 = A + (size_t)(m0 + r0_) * K + c0_ * 8;
  const unsigned short* sA1 = A + (size_t)(m0 + r1_) * K + c1_ * 8;
  const unsigned short* sB0 = Bt + (size_t)(n0 + r0_) * K + c0_ * 8;
  const unsigned short* sB1 = Bt + (size_t)(n0 + r1_) * K + c1_ * 8;
  const int ldsoff0 = (w * 2 + 0) * 512, ldsoff1 = (w * 2 + 1) * 512;

  f32x4 acc[8][4];
  const f32x4 ZV = {0.f, 0.f, 0.f, 0.f};
#pragma unroll
  for (int f = 0; f < 8; ++f)
#pragma unroll
    for (int g = 0; g < 4; ++g) acc[f][g] = ZV;

  const int aoff = (((wr * 128 + lr) * 64 + lg * 16) ^ ((lr & 7) << 4));
  const int boff = (((wc * 64 + lr) * 64 + lg * 16) ^ ((lr & 7) << 4));

  bf16x8 avA[8], bvA[4], avB[8], bvB[4];

#define STAGE(T)                                               \
  do {                                                         \
    unsigned short* ba_ = lds + ((T) & 3) * 16384;             \
    const int k0_ = (T) * 32;                                  \
    gload16(sA0 + k0_, ba_ + ldsoff0);                         \
    gload16(sA1 + k0_, ba_ + ldsoff1);                         \
    gload16(sB0 + k0_, ba_ + 8192 + ldsoff0);                  \
    gload16(sB1 + k0_, ba_ + 8192 + ldsoff1);                  \
  } while (0)

#define DSREAD(T, AN, BN)                                      \
  do {                                                         \
    const char* rb_ = (const char*)lds + ((T) & 3) * 32768;    \
    _Pragma("unroll") for (int f_ = 0; f_ < 8; ++f_)           \
      AN[f_] = *(const bf16x8*)(rb_ + aoff + f_ * 1024);       \
    _Pragma("unroll") for (int g_ = 0; g_ < 4; ++g_)           \
      BN[g_] = *(const bf16x8*)(rb_ + 16384 + boff + g_ * 1024); \
  } while (0)

#define MFMAC(AC, BC)                                          \
  do {                                                         \
    __builtin_amdgcn_s_setprio(1);                             \
    _Pragma("unroll") for (int f_ = 0; f_ < 8; ++f_)           \
      _Pragma("unroll") for (int g_ = 0; g_ < 4; ++g_)         \
        acc[f_][g_] = __builtin_amdgcn_mfma_f32_16x16x32_bf16(AC[f_], BC[g_], acc[f_][g_], 0, 0, 0); \
    __builtin_amdgcn_s_setprio(0);                             \
  } while (0)

  STAGE(0); STAGE(1); STAGE(2); STAGE(3);
  asm volatile("s_waitcnt vmcnt(8)" ::: "memory");
  bar();
  DSREAD(0, avA, bvA);

  for (int tt = 0; tt < NT - 4; tt += 2) {
    DSREAD(tt + 1, avB, bvB);
    STAGE(tt + 4);
    MFMAC(avA, bvA);
    asm volatile("s_waitcnt vmcnt(8) lgkmcnt(0)" ::: "memory");
    bar();
    DSREAD(tt + 2, avA, bvA);
    STAGE(tt + 5);
    MFMAC(avB, bvB);
    asm volatile("s_waitcnt vmcnt(8) lgkmcnt(0)" ::: "memory");
    bar();
  }
  DSREAD(93, avB, bvB);
  MFMAC(avA, bvA);
  asm volatile("s_waitcnt vmcnt(4) lgkmcnt(0)" ::: "memory");
  bar();
  DSREAD(94, avA, bvA);
  MFMAC(avB, bvB);
  asm volatile("s_waitcnt vmcnt(0) lgkmcnt(0)" ::: "memory");
  bar();
  DSREAD(95, avB, bvB);
  MFMAC(avA, bvA);
  asm volatile("s_waitcnt lgkmcnt(0)" ::: "memory");
  __builtin_amdgcn_sched_barrier(0);
  MFMAC(avB, bvB);
#undef STAGE
#undef DSREAD
#undef MFMAC

#pragma unroll
  for (int g = 0; g < 4; ++g) {
    const int n = n0 + wc * 64 + g * 16;
    const size_t jb = (size_t)(n >> 4) * 16384;
#pragma unroll
    for (int f = 0; f < 8; ++f) {
      const int m = m0 + wr * 128 + f * 16 + lg * 4;
#pragma unroll
      for (int i = 0; i < 4; ++i)
        C[jb + (size_t)(m + i) * 16 + lr] = f2bf(fmaxf(acc[f][g][i], 0.f));
    }
  }
}

// ---------------- K1 v4: MFMA GEMM1 (W1^T @ x6, bias in C-in, GLU in-lane) + fast sigm
// + cvt_pk hs pack; GEMM2 + transposed Zt store unchanged (proven round 10 + round 13) ----------
__global__ __launch_bounds__(256) void k1_fused(
    const float* __restrict__ x, const float* __restrict__ W1, const float* __restrict__ b1,
    const float* __restrict__ Theta, unsigned short* __restrict__ Zt) {
  __shared__ __align__(16) unsigned short hs[4 * 64 * 68];  // [w][n][c] pad 68
  __shared__ __align__(16) unsigned short th[3 * 16 * 72];  // [kc][o][c] pad 72
  __shared__ __align__(16) unsigned short tr[64 * 68];      // [row][n] pad 68
  const int tid = threadIdx.x, lane = tid & 63, w = tid >> 6;
  const int lr = lane & 15, lg = lane >> 4;
  const int n0 = blockIdx.x * 64;
  const int bt0 = blockIdx.y * 4;
  const int bt = bt0 + w;
  const int b = bt / 62, t = bt - b * 62;
  const bf16x8 ZB = {0, 0, 0, 0, 0, 0, 0, 0};

  // Theta^T -> LDS
  for (int idx = tid; idx < 3072; idx += 256) {
    const int kc = idx >> 10, o = (idx >> 6) & 15, c = idx & 63;
    th[kc * 1152 + o * 72 + c] = f2bf(Theta[((kc << 6) | c) * 16 + o]);
  }

  // GEMM1 A-fragments: aw[ct] = W1^T[ch=16ct+lr][q=lg*8+j]; real only lg==0, j<6
  bf16x8 aw[8];
#pragma unroll
  for (int ct = 0; ct < 8; ++ct) aw[ct] = ZB;
  if (lg == 0) {
#pragma unroll
    for (int ct = 0; ct < 8; ++ct) {
      union { unsigned short u[8]; bf16x8 v; } pk;
#pragma unroll
      for (int j = 0; j < 8; ++j) pk.u[j] = 0;
#pragma unroll
      for (int j = 0; j < 6; ++j) pk.u[j] = f2bf(W1[j * 128 + ct * 16 + lr]);
      aw[ct] = pk.v;
    }
  }
  // bias, in C/D layout: ch = 16ct + 4lg + i
  f32x4 bb[8];
#pragma unroll
  for (int ct = 0; ct < 8; ++ct)
#pragma unroll
    for (int i = 0; i < 4; ++i) bb[ct][i] = b1[ct * 16 + lg * 4 + i];

  // per n-tile: x6 B-fragment, 8 MFMAs (128 ch), GLU, write hs
#pragma unroll
  for (int nt = 0; nt < 4; ++nt) {
    bf16x8 bx = ZB;
    if (lg == 0) {
      const int n = n0 + nt * 16 + lr;
      union { unsigned short u[8]; bf16x8 v; } pk;
#pragma unroll
      for (int j = 0; j < 8; ++j) pk.u[j] = 0;
#pragma unroll
      for (int kt = 0; kt < 3; ++kt) {
        const float2 p = *(const float2*)&x[(size_t)((b * 64 + t + kt) * 1024 + n) * 2];
        pk.u[kt * 2] = f2bf(p.x);
        pk.u[kt * 2 + 1] = f2bf(p.y);
      }
      bx = pk.v;
    }
    f32x4 g[8];
#pragma unroll
    for (int ct = 0; ct < 8; ++ct) {
      g[ct] = bb[ct];
      g[ct] = __builtin_amdgcn_mfma_f32_16x16x32_bf16(aw[ct], bx, g[ct], 0, 0, 0);
    }
    // GLU: h[ch] = l * sigm(r), l at ct, r at ct+4 (same lane, same i); write hs[n][c]
    const int rowoff = (w * 64 + nt * 16 + lr) * 68;
#pragma unroll
    for (int ct = 0; ct < 4; ++ct) {
      union { unsigned u[2]; uint2 v2; } o;
      o.u[0] = cvtpk(g[ct][0] * sigm(g[ct + 4][0]), g[ct][1] * sigm(g[ct + 4][1]));
      o.u[1] = cvtpk(g[ct][2] * sigm(g[ct + 4][2]), g[ct][3] * sigm(g[ct + 4][3]));
      *(uint2*)&hs[rowoff + ct * 16 + lg * 4] = o.v2;
    }
  }
  __syncthreads();

  // GEMM2 + transposed store (unchanged, known-good)
  const f32x4 ZV = {0.f, 0.f, 0.f, 0.f};
  for (int kc = 0; kc < 3; ++kc) {
    const bf16x8 av0 = *(const bf16x8*)&th[kc * 1152 + lr * 72 + lg * 8];
    const bf16x8 av1 = *(const bf16x8*)&th[kc * 1152 + lr * 72 + 32 + lg * 8];
    f32x4 acc[4];
#pragma unroll
    for (int ns = 0; ns < 4; ++ns) acc[ns] = ZV;
#pragma unroll
    for (int ns = 0; ns < 4; ++ns) {
      const bf16x8 bv0 = *(const bf16x8*)&hs[(w * 64 + ns * 16 + lr) * 68 + lg * 8];
      const bf16x8 bv1 = *(const bf16x8*)&hs[(w * 64 + ns * 16 + lr) * 68 + 32 + lg * 8];
      acc[ns] = __builtin_amdgcn_mfma_f32_16x16x32_bf16(av0, bv0, acc[ns], 0, 0, 0);
      acc[ns] = __builtin_amdgcn_mfma_f32_16x16x32_bf16(av1, bv1, acc[ns], 0, 0, 0);
    }
    if (kc) __syncthreads();
#pragma unroll
    for (int ns = 0; ns < 4; ++ns)
#pragma unroll
      for (int i = 0; i < 4; ++i)
        tr[(w * 16 + lg * 4 + i) * 68 + ns * 16 + lr] = f2bf(acc[ns][i]);
    __syncthreads();
#pragma unroll
    for (int rd = 0; rd < 2; ++rd) {
      const int cidx = rd * 256 + tid;
      const int rl = cidx >> 3, ck = cidx & 7;
      const uint4 v = *(const uint4*)&tr[rl * 68 + ck * 8];
      *(uint4*)&Zt[(size_t)(bt0 * 16 + rl) * 3072 + kc * 1024 + n0 + ck * 8] = v;
    }
  }
}

// ---------------- K3: stage-3 conv+GLU; A-frags direct from global, only W2 in LDS ----------------
__global__ __launch_bounds__(256) void k3_out(
    const unsigned short* __restrict__ accb, const float* __restrict__ W2,
    const float* __restrict__ b2, float* __restrict__ out) {
  __shared__ __align__(16) unsigned short sW[128 * 72];
  const int tid = threadIdx.x, lane = tid & 63, w = tid >> 6;
  const int lr = lane & 15, lg = lane >> 4;
  const int n0 = blockIdx.x * 256;
  const int btp = blockIdx.y;
  const int b = btp / 60, tt = btp - b * 60;
  for (int idx = tid; idx < 2048; idx += 256) {
    const int ch = idx >> 4, k = 48 + (idx & 15);
    sW[ch * 72 + k] = 0;
  }
  for (int idx = tid; idx < 6144; idx += 256) {
    const int k = idx >> 7, ch = idx & 127;
    sW[ch * 72 + k] = f2bf(W2[idx]);
  }
  const int rowb = n0 + w * 64;
  const bf16x8 ZB = {0, 0, 0, 0, 0, 0, 0, 0};
  bf16x8 av[4][2];
#pragma unroll
  for (int f = 0; f < 4; ++f)
#pragma unroll
    for (int hh = 0; hh < 2; ++hh) {
      const int gk = hh * 32 + lg * 8;
      const int kt = gk >> 4, ci = gk & 15;
      av[f][hh] = ZB;
      if (kt < 3)
        av[f][hh] = *(const bf16x8*)&accb[(size_t)(b * 62 + tt + kt) * 16384 +
                                          (size_t)(rowb + f * 16 + lr) * 16 + ci];
    }
  __syncthreads();
  const size_t obase = (size_t)(b * 60 + tt) * 65536;
  const f32x4 ZV = {0.f, 0.f, 0.f, 0.f};
#pragma unroll
  for (int gl = 0; gl < 4; ++gl) {
    const int chl = gl * 16 + lr;
    const bf16x8 bl0 = *(const bf16x8*)&sW[chl * 72 + lg * 8];
    const bf16x8 bl1 = *(const bf16x8*)&sW[chl * 72 + 32 + lg * 8];
    const bf16x8 br0 = *(const bf16x8*)&sW[(64 + chl) * 72 + lg * 8];
    const bf16x8 br1 = *(const bf16x8*)&sW[(64 + chl) * 72 + 32 + lg * 8];
    f32x4 aL[4], aR[4];
#pragma unroll
    for (int f = 0; f < 4; ++f) { aL[f] = ZV; aR[f] = ZV; }
#pragma unroll
    for (int f = 0; f < 4; ++f) {
      aL[f] = __builtin_amdgcn_mfma_f32_16x16x32_bf16(av[f][0], bl0, aL[f], 0, 0, 0);
      aL[f] = __builtin_amdgcn_mfma_f32_16x16x32_bf16(av[f][1], bl1, aL[f], 0, 0, 0);
      aR[f] = __builtin_amdgcn_mfma_f32_16x16x32_bf16(av[f][0], br0, aR[f], 0, 0, 0);
      aR[f] = __builtin_amdgcn_mfma_f32_16x16x32_bf16(av[f][1], br1, aR[f], 0, 0, 0);
    }
    const float bbl = b2[chl], bbr = b2[64 + chl];
#pragma unroll
    for (int f = 0; f < 4; ++f)
#pragma unroll
      for (int i = 0; i < 4; ++i) {
        const float pl = aL[f][i] + bbl;
        const float pr = aR[f][i] + bbr;
        out[obase + (size_t)(rowb + f * 16 + lg * 4 + i) * 64 + chl] = pl * sigm(pr);
      }
  }
}

extern "C" void kernel_launch(void* const* d_in, const int* in_sizes, int n_in,
                              void* d_out, int out_size, void* d_ws, size_t ws_size,
                              hipStream_t stream) {
  const float* x    = (const float*)d_in[0];
  const float* cheb = (const float*)d_in[1];
  const float* W1   = (const float*)d_in[2];
  const float* b1   = (const float*)d_in[3];
  const float* Th   = (const float*)d_in[4];
  const float* W2   = (const float*)d_in[5];
  const float* b2   = (const float*)d_in[6];
  float* out = (float*)d_out;

  char* ws = (char*)d_ws;
  const size_t MB = 1u << 20;
  unsigned short* cb1  = (unsigned short*)(ws);             // 2 MB  cheb1 bf16
  unsigned short* cb2  = (unsigned short*)(ws + 2 * MB);    // 2 MB  cheb2 bf16
  unsigned short* Pbig = (unsigned short*)(ws + 4 * MB);    // 6 MB  (1024 x 3072 bf16)
  unsigned short* t0   = (unsigned short*)(ws + 10 * MB);   // 2 MB  cheb0^T
  unsigned short* t1   = (unsigned short*)(ws + 12 * MB);   // 2 MB  cheb1^T
  unsigned short* Qb   = (unsigned short*)(ws + 14 * MB);   // 2 MB  Q=cheb2@cheb1 (dead before accb)
  unsigned short* accb = (unsigned short*)(ws + 14 * MB);   // 32.5 MB (992 x 1024 x 16), overlaps Qb
  float*          P1f  = (float*)(ws + 48 * MB);            // 8 MB fp32 split partials (P1)
  float*          Qf   = (float*)(ws + 64 * MB);            // 8 MB fp32 split partials (Q)
  float*          P2f  = (float*)(ws + 80 * MB);            // 8 MB fp32 split partials (P2)
  unsigned short* Zt   = (unsigned short*)d_out;            // 97.5 MB scratch in out buf

  k0t<<<dim3(16, 16, 3), 256, 0, stream>>>(cheb, cb1, cb2, Pbig, t0, t1);
  gemm_splitk<<<dim3(64, 2, 2), 256, 0, stream>>>(cb1, t0, P1f, cb2, t1, Qf);
  reducep<<<dim3(1024, 1, 2), 256, 0, stream>>>(P1f, Pbig, 3072, 1024, Qf, Qb, 1024, 0);
  gemm_splitk<<<dim3(64, 2, 1), 256, 0, stream>>>(Qb, t0, P2f, Qb, t0, P2f);
  reducep<<<dim3(1024, 1, 1), 256, 0, stream>>>(P2f, Pbig, 3072, 2048, P2f, Pbig, 3072, 2048);
  k1_fused<<<dim3(16, 248), 256, 0, stream>>>(x, W1, b1, Th, Zt);
  gemm_big<<<dim3(248), dim3(512), 0, stream>>>(Pbig, Zt, accb);
  k3_out<<<dim3(4, 960), 256, 0, stream>>>(accb, W2, b2, out);
}

// Round 15
// 276.921 us; speedup vs baseline: 1.0203x; 1.0203x over previous
//
#include <hip/hip_runtime.h>
#include <stdint.h>

typedef __attribute__((ext_vector_type(8))) short bf16x8;
typedef __attribute__((ext_vector_type(4))) float f32x4;

__device__ __forceinline__ unsigned short f2bf(float f) {
  union { float f; unsigned u; } v; v.f = f;
  unsigned r = v.u + 0x7FFFu + ((v.u >> 16) & 1u);
  return (unsigned short)(r >> 16);
}

// fast sigmoid: v_rcp_f32 (1 inst) instead of IEEE div sequence (~9 inst).
__device__ __forceinline__ float sigm(float x) {
  return __builtin_amdgcn_rcpf(1.0f + __expf(-x));
}

__device__ __forceinline__ unsigned cvtpk(float lo, float hi) {
  unsigned u;
  asm("v_cvt_pk_bf16_f32 %0, %1, %2" : "=v"(u) : "v"(lo), "v"(hi));
  return u;
}

__device__ __forceinline__ void gload16(const void* g, void* l) {
  __builtin_amdgcn_global_load_lds((const __attribute__((address_space(1))) void*)g,
                                   (__attribute__((address_space(3))) void*)l, 16, 0, 0);
}

__device__ __forceinline__ void bar() {
  __builtin_amdgcn_sched_barrier(0);
  __builtin_amdgcn_s_barrier();
  __builtin_amdgcn_sched_barrier(0);
}

// ---------------- K0T: cheb fp32 -> bf16 (normal + transposed), one pass ----------------
__global__ void k0t(const float* __restrict__ cheb, unsigned short* __restrict__ cb1,
                    unsigned short* __restrict__ cb2, unsigned short* __restrict__ Pbig,
                    unsigned short* __restrict__ t0, unsigned short* __restrict__ t1) {
  __shared__ unsigned short t[64][65];
  const int z = blockIdx.z;
  const int c = threadIdx.x & 63, r4 = threadIdx.x >> 6;
  const int r0 = blockIdx.y * 64, c0 = blockIdx.x * 64;
  const float* src = cheb + (size_t)z * 1048576;
#pragma unroll
  for (int r = 0; r < 64; r += 4) {
    const int rr = r0 + r + r4;
    const unsigned short h = f2bf(src[(size_t)rr * 1024 + c0 + c]);
    t[r + r4][c] = h;
    if (z == 0) Pbig[(size_t)rr * 3072 + c0 + c] = h;
    else if (z == 1) cb1[(size_t)rr * 1024 + c0 + c] = h;
    else cb2[(size_t)rr * 1024 + c0 + c] = h;
  }
  __syncthreads();
  if (z == 2) return;
  unsigned short* dst = z ? t1 : t0;
#pragma unroll
  for (int r = 0; r < 64; r += 4)
    dst[(size_t)(c0 + r + r4) * 1024 + r0 + c] = t[c][r + r4];
}

// ---------------- gemm_splitk: 128^2 tile, K=1024 split into 2 chunks of 512 ----------------
__global__ __launch_bounds__(256) void gemm_splitk(
    const unsigned short* __restrict__ A1, const unsigned short* __restrict__ B1,
    float* __restrict__ C1,
    const unsigned short* __restrict__ A2, const unsigned short* __restrict__ B2,
    float* __restrict__ C2) {
  __shared__ __align__(16) unsigned short sA[128 * 32];
  __shared__ __align__(16) unsigned short sB[128 * 32];
  const unsigned short* Ap = blockIdx.z ? A2 : A1;
  const unsigned short* Bp = blockIdx.z ? B2 : B1;
  float* Cp = blockIdx.z ? C2 : C1;
  const int mb = blockIdx.x & 7, nb = blockIdx.x >> 3, ks = blockIdx.y;
  const int tid = threadIdx.x;
  const int lane = tid & 63;
  const int w = tid >> 6;
  const int m0 = mb * 128, n0 = nb * 128;
  const int wm = (w >> 1) * 64, wn = (w & 1) * 64;
  const int lr = lane & 15, lg = lane >> 4;
  const f32x4 ZV = {0.f, 0.f, 0.f, 0.f};
  f32x4 acc[4][4];
#pragma unroll
  for (int f = 0; f < 4; ++f)
#pragma unroll
    for (int g = 0; g < 4; ++g) acc[f][g] = ZV;
  const int r2 = tid >> 2, kp = tid & 3;
  const size_t rowA0 = (size_t)(m0 + r2) * 1024;
  const size_t rowA1 = (size_t)(m0 + 64 + r2) * 1024;
  const size_t rowB0 = (size_t)(n0 + r2) * 1024;
  const size_t rowB1 = (size_t)(n0 + 64 + r2) * 1024;
  unsigned short* la = &sA[w * 512];
  unsigned short* lb = &sB[w * 512];
  const int kbase = ks * 512;
  for (int k0 = kbase; k0 < kbase + 512; k0 += 32) {
    const int kc = k0 + kp * 8;
    gload16(Ap + rowA0 + kc, la);
    gload16(Ap + rowA1 + kc, la + 2048);
    gload16(Bp + rowB0 + kc, lb);
    gload16(Bp + rowB1 + kc, lb + 2048);
    __syncthreads();
    bf16x8 av[4], bv[4];
#pragma unroll
    for (int f = 0; f < 4; ++f)
      av[f] = *(const bf16x8*)&sA[(wm + f * 16 + lr) * 32 + lg * 8];
#pragma unroll
    for (int g = 0; g < 4; ++g)
      bv[g] = *(const bf16x8*)&sB[(wn + g * 16 + lr) * 32 + lg * 8];
#pragma unroll
    for (int f = 0; f < 4; ++f)
#pragma unroll
      for (int g = 0; g < 4; ++g)
        acc[f][g] = __builtin_amdgcn_mfma_f32_16x16x32_bf16(av[f], bv[g], acc[f][g], 0, 0, 0);
    __syncthreads();
  }
  float* Cb = Cp + (size_t)ks * 1048576;
#pragma unroll
  for (int f = 0; f < 4; ++f) {
    const int m = m0 + wm + f * 16 + lg * 4;
#pragma unroll
    for (int g = 0; g < 4; ++g) {
      const int col = n0 + wn + g * 16 + lr;
#pragma unroll
      for (int i = 0; i < 4; ++i)
        Cb[(size_t)(m + i) * 1024 + col] = acc[f][g][i];
    }
  }
}

// ---------------- reducep: sum 2 fp32 split-partials -> bf16 dst (deterministic) ----------------
__global__ void reducep(const float* __restrict__ S1, unsigned short* __restrict__ D1, int ld1, int co1,
                        const float* __restrict__ S2, unsigned short* __restrict__ D2, int ld2, int co2) {
  const float* S = blockIdx.z ? S2 : S1;
  unsigned short* D = blockIdx.z ? D2 : D1;
  const int ld = blockIdx.z ? ld2 : ld1;
  const int co = blockIdx.z ? co2 : co1;
  const int e = (blockIdx.x * 256 + threadIdx.x) * 4;
  const float4 a = *(const float4*)&S[e];
  const float4 b = *(const float4*)&S[1048576 + e];
  const int row = e >> 10, col = e & 1023;
  ushort4 o;
  o.x = f2bf(a.x + b.x);
  o.y = f2bf(a.y + b.y);
  o.z = f2bf(a.z + b.z);
  o.w = f2bf(a.w + b.w);
  *(ushort4*)&D[(size_t)row * ld + co + col] = o;
}

// ---------------- gemm_big: 256x256 tile, BK=32, depth-4 LDS, reg dbuf, 1 bar/tile ----------------
// (round-6 proven version, verbatim — ~105 us)
__device__ __forceinline__ void dec_chunk(int s, int& row, int& c) {
  const int r3 = (((s >> 2) ^ (s >> 4)) & 1) | (((s >> 3) & 1) << 1) | (((s >> 4) & 1) << 2);
  const int u = s ^ r3;
  row = u >> 2;
  c = u & 3;
}

__global__ __launch_bounds__(512, 2) void gemm_big(
    const unsigned short* __restrict__ A, const unsigned short* __restrict__ Bt,
    unsigned short* __restrict__ C) {
  constexpr int K = 3072, NT = 96;  // NT = K/32
  __shared__ __align__(16) unsigned short lds[4 * 16384];  // 128 KiB: 4 bufs x [A 16KB | B 16KB]
  const int tid = threadIdx.x;
  const int lane = tid & 63, w = tid >> 6;
  const int wr = w >> 2, wc = w & 3;
  const int lr = lane & 15, lg = lane >> 4;
  const int lin = blockIdx.x;                 // 248 blocks: XCD-bijective swizzle (248 = 8*31)
  const int v = (lin & 7) * 31 + (lin >> 3);
  const int mb = v & 3, nb = v >> 2;
  const int m0 = mb * 256, n0 = nb * 256;

  int r0_, c0_, r1_, c1_;
  dec_chunk((w * 2 + 0) * 64 + lane, r0_, c0_);
  dec_chunk((w * 2 + 1) * 64 + lane, r1_, c1_);
  const unsigned short* sA0 = A + (size_t)(m0 + r0_) * K + c0_ * 8;
  const unsigned short* sA1 = A + (size_t)(m0 + r1_) * K + c1_ * 8;
  const unsigned short* sB0 = Bt + (size_t)(n0 + r0_) * K + c0_ * 8;
  const unsigned short* sB1 = Bt + (size_t)(n0 + r1_) * K + c1_ * 8;
  const int ldsoff0 = (w * 2 + 0) * 512, ldsoff1 = (w * 2 + 1) * 512;

  f32x4 acc[8][4];
  const f32x4 ZV = {0.f, 0.f, 0.f, 0.f};
#pragma unroll
  for (int f = 0; f < 8; ++f)
#pragma unroll
    for (int g = 0; g < 4; ++g) acc[f][g] = ZV;

  const int aoff = (((wr * 128 + lr) * 64 + lg * 16) ^ ((lr & 7) << 4));
  const int boff = (((wc * 64 + lr) * 64 + lg * 16) ^ ((lr & 7) << 4));

  bf16x8 avA[8], bvA[4], avB[8], bvB[4];

#define STAGE(T)                                               \
  do {                                                         \
    unsigned short* ba_ = lds + ((T) & 3) * 16384;             \
    const int k0_ = (T) * 32;                                  \
    gload16(sA0 + k0_, ba_ + ldsoff0);                         \
    gload16(sA1 + k0_, ba_ + ldsoff1);                         \
    gload16(sB0 + k0_, ba_ + 8192 + ldsoff0);                  \
    gload16(sB1 + k0_, ba_ + 8192 + ldsoff1);                  \
  } while (0)

#define DSREAD(T, AN, BN)                                      \
  do {                                                         \
    const char* rb_ = (const char*)lds + ((T) & 3) * 32768;    \
    _Pragma("unroll") for (int f_ = 0; f_ < 8; ++f_)           \
      AN[f_] = *(const bf16x8*)(rb_ + aoff + f_ * 1024);       \
    _Pragma("unroll") for (int g_ = 0; g_ < 4; ++g_)           \
      BN[g_] = *(const bf16x8*)(rb_ + 16384 + boff + g_ * 1024); \
  } while (0)

#define MFMAC(AC, BC)                                          \
  do {                                                         \
    __builtin_amdgcn_s_setprio(1);                             \
    _Pragma("unroll") for (int f_ = 0; f_ < 8; ++f_)           \
      _Pragma("unroll") for (int g_ = 0; g_ < 4; ++g_)         \
        acc[f_][g_] = __builtin_amdgcn_mfma_f32_16x16x32_bf16(AC[f_], BC[g_], acc[f_][g_], 0, 0, 0); \
    __builtin_amdgcn_s_setprio(0);                             \
  } while (0)

  STAGE(0); STAGE(1); STAGE(2); STAGE(3);
  asm volatile("s_waitcnt vmcnt(8)" ::: "memory");
  bar();
  DSREAD(0, avA, bvA);

  for (int tt = 0; tt < NT - 4; tt += 2) {
    DSREAD(tt + 1, avB, bvB);
    STAGE(tt + 4);
    MFMAC(avA, bvA);
    asm volatile("s_waitcnt vmcnt(8) lgkmcnt(0)" ::: "memory");
    bar();
    DSREAD(tt + 2, avA, bvA);
    STAGE(tt + 5);
    MFMAC(avB, bvB);
    asm volatile("s_waitcnt vmcnt(8) lgkmcnt(0)" ::: "memory");
    bar();
  }
  DSREAD(93, avB, bvB);
  MFMAC(avA, bvA);
  asm volatile("s_waitcnt vmcnt(4) lgkmcnt(0)" ::: "memory");
  bar();
  DSREAD(94, avA, bvA);
  MFMAC(avB, bvB);
  asm volatile("s_waitcnt vmcnt(0) lgkmcnt(0)" ::: "memory");
  bar();
  DSREAD(95, avB, bvB);
  MFMAC(avA, bvA);
  asm volatile("s_waitcnt lgkmcnt(0)" ::: "memory");
  __builtin_amdgcn_sched_barrier(0);
  MFMAC(avB, bvB);
#undef STAGE
#undef DSREAD
#undef MFMAC

#pragma unroll
  for (int g = 0; g < 4; ++g) {
    const int n = n0 + wc * 64 + g * 16;
    const size_t jb = (size_t)(n >> 4) * 16384;
#pragma unroll
    for (int f = 0; f < 8; ++f) {
      const int m = m0 + wr * 128 + f * 16 + lg * 4;
#pragma unroll
      for (int i = 0; i < 4; ++i)
        C[jb + (size_t)(m + i) * 16 + lr] = f2bf(fmaxf(acc[f][g][i], 0.f));
    }
  }
}

// ---------------- K1 v5: VALU GLU (round-13) + operand-swapped GEMM2 -> direct Zt store ----------
// GEMM2: acc = mfma(A=hs_frag, B=th_frag) => D rows = n (lg*4+i), cols = o (lr).
// Lane owns 4 consecutive n for fixed o-row -> cvtpk pair -> one 8B store; tr bounce deleted.
__global__ __launch_bounds__(256) void k1_fused(
    const float* __restrict__ x, const float* __restrict__ W1, const float* __restrict__ b1,
    const float* __restrict__ Theta, unsigned short* __restrict__ Zt) {
  __shared__ __align__(16) unsigned short hs[4 * 64 * 68];  // [w][n][c] pad 68
  __shared__ __align__(16) unsigned short th[3 * 16 * 72];  // [kc][o][c] pad 72
  const int tid = threadIdx.x, lane = tid & 63, w = tid >> 6;
  const int n0 = blockIdx.x * 64;
  const int bt0 = blockIdx.y * 4;
  const int bt = bt0 + w;
  const int b = bt / 62, t = bt - b * 62;
  float xv[6];
#pragma unroll
  for (int kt = 0; kt < 3; ++kt) {
    const float2 p = *(const float2*)&x[(size_t)((b * 64 + t + kt) * 1024 + n0 + lane) * 2];
    xv[kt * 2] = p.x;
    xv[kt * 2 + 1] = p.y;
  }
  float h[64];
#pragma unroll
  for (int ch = 0; ch < 64; ++ch) {
    float l = b1[ch], r = b1[64 + ch];
#pragma unroll
    for (int q = 0; q < 6; ++q) {  // uniform indices -> scalar loads
      l += xv[q] * W1[q * 128 + ch];
      r += xv[q] * W1[q * 128 + 64 + ch];
    }
    h[ch] = l * sigm(r);
  }
  // pack h -> hs via v_cvt_pk_bf16_f32 (2 values/inst, RNE — same as f2bf)
#pragma unroll
  for (int c8 = 0; c8 < 8; ++c8) {
    union { unsigned u[4]; uint4 v; } pk;
#pragma unroll
    for (int j = 0; j < 4; ++j)
      pk.u[j] = cvtpk(h[c8 * 8 + 2 * j], h[c8 * 8 + 2 * j + 1]);
    *(uint4*)&hs[(w * 64 + lane) * 68 + c8 * 8] = pk.v;
  }
  for (int idx = tid; idx < 3072; idx += 256) {
    const int kc = idx >> 10, o = (idx >> 6) & 15, c = idx & 63;
    th[kc * 1152 + o * 72 + c] = f2bf(Theta[((kc << 6) | c) * 16 + o]);
  }
  __syncthreads();
  const int lr = lane & 15, lg = lane >> 4;
  const f32x4 ZV = {0.f, 0.f, 0.f, 0.f};
  // per-wave output rows: (bt*16 + o), o = lr; n = ns*16 + lg*4 + i (consecutive per lane)
  const size_t rowbase = ((size_t)bt * 16 + lr) * 3072 + n0 + lg * 4;
  for (int kc = 0; kc < 3; ++kc) {
    const bf16x8 tb0 = *(const bf16x8*)&th[kc * 1152 + lr * 72 + lg * 8];
    const bf16x8 tb1 = *(const bf16x8*)&th[kc * 1152 + lr * 72 + 32 + lg * 8];
    f32x4 acc[4];
#pragma unroll
    for (int ns = 0; ns < 4; ++ns) acc[ns] = ZV;
#pragma unroll
    for (int ns = 0; ns < 4; ++ns) {
      const bf16x8 ha0 = *(const bf16x8*)&hs[(w * 64 + ns * 16 + lr) * 68 + lg * 8];
      const bf16x8 ha1 = *(const bf16x8*)&hs[(w * 64 + ns * 16 + lr) * 68 + 32 + lg * 8];
      acc[ns] = __builtin_amdgcn_mfma_f32_16x16x32_bf16(ha0, tb0, acc[ns], 0, 0, 0);
      acc[ns] = __builtin_amdgcn_mfma_f32_16x16x32_bf16(ha1, tb1, acc[ns], 0, 0, 0);
    }
#pragma unroll
    for (int ns = 0; ns < 4; ++ns) {
      union { unsigned u[2]; uint2 v2; } o2;
      o2.u[0] = cvtpk(acc[ns][0], acc[ns][1]);
      o2.u[1] = cvtpk(acc[ns][2], acc[ns][3]);
      *(uint2*)&Zt[rowbase + (size_t)kc * 1024 + ns * 16] = o2.v2;
    }
  }
}

// ---------------- K3: stage-3 conv+GLU; bias in acc-init; A-frags direct from global ----------------
__global__ __launch_bounds__(256) void k3_out(
    const unsigned short* __restrict__ accb, const float* __restrict__ W2,
    const float* __restrict__ b2, float* __restrict__ out) {
  __shared__ __align__(16) unsigned short sW[128 * 72];
  const int tid = threadIdx.x, lane = tid & 63, w = tid >> 6;
  const int lr = lane & 15, lg = lane >> 4;
  const int n0 = blockIdx.x * 256;
  const int btp = blockIdx.y;
  const int b = btp / 60, tt = btp - b * 60;
  for (int idx = tid; idx < 2048; idx += 256) {
    const int ch = idx >> 4, k = 48 + (idx & 15);
    sW[ch * 72 + k] = 0;
  }
  for (int idx = tid; idx < 6144; idx += 256) {
    const int k = idx >> 7, ch = idx & 127;
    sW[ch * 72 + k] = f2bf(W2[idx]);
  }
  const int rowb = n0 + w * 64;
  const bf16x8 ZB = {0, 0, 0, 0, 0, 0, 0, 0};
  bf16x8 av[4][2];
#pragma unroll
  for (int f = 0; f < 4; ++f)
#pragma unroll
    for (int hh = 0; hh < 2; ++hh) {
      const int gk = hh * 32 + lg * 8;
      const int kt = gk >> 4, ci = gk & 15;
      av[f][hh] = ZB;
      if (kt < 3)
        av[f][hh] = *(const bf16x8*)&accb[(size_t)(b * 62 + tt + kt) * 16384 +
                                          (size_t)(rowb + f * 16 + lr) * 16 + ci];
    }
  __syncthreads();
  const size_t obase = (size_t)(b * 60 + tt) * 65536;
#pragma unroll
  for (int gl = 0; gl < 4; ++gl) {
    const int chl = gl * 16 + lr;
    const bf16x8 bl0 = *(const bf16x8*)&sW[chl * 72 + lg * 8];
    const bf16x8 bl1 = *(const bf16x8*)&sW[chl * 72 + 32 + lg * 8];
    const bf16x8 br0 = *(const bf16x8*)&sW[(64 + chl) * 72 + lg * 8];
    const bf16x8 br1 = *(const bf16x8*)&sW[(64 + chl) * 72 + 32 + lg * 8];
    const float bbl = b2[chl], bbr = b2[64 + chl];
    const f32x4 BL = {bbl, bbl, bbl, bbl};
    const f32x4 BR = {bbr, bbr, bbr, bbr};
    f32x4 aL[4], aR[4];
#pragma unroll
    for (int f = 0; f < 4; ++f) { aL[f] = BL; aR[f] = BR; }
#pragma unroll
    for (int f = 0; f < 4; ++f) {
      aL[f] = __builtin_amdgcn_mfma_f32_16x16x32_bf16(av[f][0], bl0, aL[f], 0, 0, 0);
      aL[f] = __builtin_amdgcn_mfma_f32_16x16x32_bf16(av[f][1], bl1, aL[f], 0, 0, 0);
      aR[f] = __builtin_amdgcn_mfma_f32_16x16x32_bf16(av[f][0], br0, aR[f], 0, 0, 0);
      aR[f] = __builtin_amdgcn_mfma_f32_16x16x32_bf16(av[f][1], br1, aR[f], 0, 0, 0);
    }
#pragma unroll
    for (int f = 0; f < 4; ++f)
#pragma unroll
      for (int i = 0; i < 4; ++i)
        out[obase + (size_t)(rowb + f * 16 + lg * 4 + i) * 64 + chl] =
            aL[f][i] * sigm(aR[f][i]);
  }
}

extern "C" void kernel_launch(void* const* d_in, const int* in_sizes, int n_in,
                              void* d_out, int out_size, void* d_ws, size_t ws_size,
                              hipStream_t stream) {
  const float* x    = (const float*)d_in[0];
  const float* cheb = (const float*)d_in[1];
  const float* W1   = (const float*)d_in[2];
  const float* b1   = (const float*)d_in[3];
  const float* Th   = (const float*)d_in[4];
  const float* W2   = (const float*)d_in[5];
  const float* b2   = (const float*)d_in[6];
  float* out = (float*)d_out;

  char* ws = (char*)d_ws;
  const size_t MB = 1u << 20;
  unsigned short* cb1  = (unsigned short*)(ws);             // 2 MB  cheb1 bf16
  unsigned short* cb2  = (unsigned short*)(ws + 2 * MB);    // 2 MB  cheb2 bf16
  unsigned short* Pbig = (unsigned short*)(ws + 4 * MB);    // 6 MB  (1024 x 3072 bf16)
  unsigned short* t0   = (unsigned short*)(ws + 10 * MB);   // 2 MB  cheb0^T
  unsigned short* t1   = (unsigned short*)(ws + 12 * MB);   // 2 MB  cheb1^T
  unsigned short* Qb   = (unsigned short*)(ws + 14 * MB);   // 2 MB  Q=cheb2@cheb1 (dead before accb)
  unsigned short* accb = (unsigned short*)(ws + 14 * MB);   // 32.5 MB (992 x 1024 x 16), overlaps Qb
  float*          P1f  = (float*)(ws + 48 * MB);            // 8 MB fp32 split partials (P1)
  float*          Qf   = (float*)(ws + 64 * MB);            // 8 MB fp32 split partials (Q)
  float*          P2f  = (float*)(ws + 80 * MB);            // 8 MB fp32 split partials (P2)
  unsigned short* Zt   = (unsigned short*)d_out;            // 97.5 MB scratch in out buf

  k0t<<<dim3(16, 16, 3), 256, 0, stream>>>(cheb, cb1, cb2, Pbig, t0, t1);
  gemm_splitk<<<dim3(64, 2, 2), 256, 0, stream>>>(cb1, t0, P1f, cb2, t1, Qf);
  reducep<<<dim3(1024, 1, 2), 256, 0, stream>>>(P1f, Pbig, 3072, 1024, Qf, Qb, 1024, 0);
  gemm_splitk<<<dim3(64, 2, 1), 256, 0, stream>>>(Qb, t0, P2f, Qb, t0, P2f);
  reducep<<<dim3(1024, 1, 1), 256, 0, stream>>>(P2f, Pbig, 3072, 2048, P2f, Pbig, 3072, 2048);
  k1_fused<<<dim3(16, 248), 256, 0, stream>>>(x, W1, b1, Th, Zt);
  gemm_big<<<dim3(248), dim3(512), 0, stream>>>(Pbig, Zt, accb);
  k3_out<<<dim3(4, 960), 256, 0, stream>>>(accb, W2, b2, out);
}

// Round 16
// 273.061 us; speedup vs baseline: 1.0347x; 1.0141x over previous
//
#include <hip/hip_runtime.h>
#include <stdint.h>

typedef __attribute__((ext_vector_type(8))) short bf16x8;
typedef __attribute__((ext_vector_type(4))) float f32x4;

__device__ __forceinline__ unsigned short f2bf(float f) {
  union { float f; unsigned u; } v; v.f = f;
  unsigned r = v.u + 0x7FFFu + ((v.u >> 16) & 1u);
  return (unsigned short)(r >> 16);
}

// fast sigmoid: v_rcp_f32 (1 inst) instead of IEEE div sequence (~9 inst).
// rcp rel-err ~1e-7, invisible after bf16/fp32 output rounding.
__device__ __forceinline__ float sigm(float x) {
  return __builtin_amdgcn_rcpf(1.0f + __expf(-x));
}

__device__ __forceinline__ unsigned cvtpk(float lo, float hi) {
  unsigned u;
  asm("v_cvt_pk_bf16_f32 %0, %1, %2" : "=v"(u) : "v"(lo), "v"(hi));
  return u;
}

__device__ __forceinline__ void gload16(const void* g, void* l) {
  __builtin_amdgcn_global_load_lds((const __attribute__((address_space(1))) void*)g,
                                   (__attribute__((address_space(3))) void*)l, 16, 0, 0);
}

__device__ __forceinline__ void bar() {
  __builtin_amdgcn_sched_barrier(0);
  __builtin_amdgcn_s_barrier();
  __builtin_amdgcn_sched_barrier(0);
}

// ---------------- K0T: cheb fp32 -> bf16 (normal + transposed), one pass ----------------
__global__ void k0t(const float* __restrict__ cheb, unsigned short* __restrict__ cb1,
                    unsigned short* __restrict__ cb2, unsigned short* __restrict__ Pbig,
                    unsigned short* __restrict__ t0, unsigned short* __restrict__ t1) {
  __shared__ unsigned short t[64][65];
  const int z = blockIdx.z;
  const int c = threadIdx.x & 63, r4 = threadIdx.x >> 6;
  const int r0 = blockIdx.y * 64, c0 = blockIdx.x * 64;
  const float* src = cheb + (size_t)z * 1048576;
#pragma unroll
  for (int r = 0; r < 64; r += 4) {
    const int rr = r0 + r + r4;
    const unsigned short h = f2bf(src[(size_t)rr * 1024 + c0 + c]);
    t[r + r4][c] = h;
    if (z == 0) Pbig[(size_t)rr * 3072 + c0 + c] = h;
    else if (z == 1) cb1[(size_t)rr * 1024 + c0 + c] = h;
    else cb2[(size_t)rr * 1024 + c0 + c] = h;
  }
  __syncthreads();
  if (z == 2) return;
  unsigned short* dst = z ? t1 : t0;
#pragma unroll
  for (int r = 0; r < 64; r += 4)
    dst[(size_t)(c0 + r + r4) * 1024 + r0 + c] = t[c][r + r4];
}

// ---------------- gemm_splitk: 128^2 tile, K=1024 split into 2 chunks of 512 ----------------
__global__ __launch_bounds__(256) void gemm_splitk(
    const unsigned short* __restrict__ A1, const unsigned short* __restrict__ B1,
    float* __restrict__ C1,
    const unsigned short* __restrict__ A2, const unsigned short* __restrict__ B2,
    float* __restrict__ C2) {
  __shared__ __align__(16) unsigned short sA[128 * 32];
  __shared__ __align__(16) unsigned short sB[128 * 32];
  const unsigned short* Ap = blockIdx.z ? A2 : A1;
  const unsigned short* Bp = blockIdx.z ? B2 : B1;
  float* Cp = blockIdx.z ? C2 : C1;
  const int mb = blockIdx.x & 7, nb = blockIdx.x >> 3, ks = blockIdx.y;
  const int tid = threadIdx.x;
  const int lane = tid & 63;
  const int w = tid >> 6;
  const int m0 = mb * 128, n0 = nb * 128;
  const int wm = (w >> 1) * 64, wn = (w & 1) * 64;
  const int lr = lane & 15, lg = lane >> 4;
  const f32x4 ZV = {0.f, 0.f, 0.f, 0.f};
  f32x4 acc[4][4];
#pragma unroll
  for (int f = 0; f < 4; ++f)
#pragma unroll
    for (int g = 0; g < 4; ++g) acc[f][g] = ZV;
  const int r2 = tid >> 2, kp = tid & 3;
  const size_t rowA0 = (size_t)(m0 + r2) * 1024;
  const size_t rowA1 = (size_t)(m0 + 64 + r2) * 1024;
  const size_t rowB0 = (size_t)(n0 + r2) * 1024;
  const size_t rowB1 = (size_t)(n0 + 64 + r2) * 1024;
  unsigned short* la = &sA[w * 512];
  unsigned short* lb = &sB[w * 512];
  const int kbase = ks * 512;
  for (int k0 = kbase; k0 < kbase + 512; k0 += 32) {
    const int kc = k0 + kp * 8;
    gload16(Ap + rowA0 + kc, la);
    gload16(Ap + rowA1 + kc, la + 2048);
    gload16(Bp + rowB0 + kc, lb);
    gload16(Bp + rowB1 + kc, lb + 2048);
    __syncthreads();
    bf16x8 av[4], bv[4];
#pragma unroll
    for (int f = 0; f < 4; ++f)
      av[f] = *(const bf16x8*)&sA[(wm + f * 16 + lr) * 32 + lg * 8];
#pragma unroll
    for (int g = 0; g < 4; ++g)
      bv[g] = *(const bf16x8*)&sB[(wn + g * 16 + lr) * 32 + lg * 8];
#pragma unroll
    for (int f = 0; f < 4; ++f)
#pragma unroll
      for (int g = 0; g < 4; ++g)
        acc[f][g] = __builtin_amdgcn_mfma_f32_16x16x32_bf16(av[f], bv[g], acc[f][g], 0, 0, 0);
    __syncthreads();
  }
  float* Cb = Cp + (size_t)ks * 1048576;
#pragma unroll
  for (int f = 0; f < 4; ++f) {
    const int m = m0 + wm + f * 16 + lg * 4;
#pragma unroll
    for (int g = 0; g < 4; ++g) {
      const int col = n0 + wn + g * 16 + lr;
#pragma unroll
      for (int i = 0; i < 4; ++i)
        Cb[(size_t)(m + i) * 1024 + col] = acc[f][g][i];
    }
  }
}

// ---------------- reducep: sum 2 fp32 split-partials -> bf16 dst (deterministic) ----------------
__global__ void reducep(const float* __restrict__ S1, unsigned short* __restrict__ D1, int ld1, int co1,
                        const float* __restrict__ S2, unsigned short* __restrict__ D2, int ld2, int co2) {
  const float* S = blockIdx.z ? S2 : S1;
  unsigned short* D = blockIdx.z ? D2 : D1;
  const int ld = blockIdx.z ? ld2 : ld1;
  const int co = blockIdx.z ? co2 : co1;
  const int e = (blockIdx.x * 256 + threadIdx.x) * 4;
  const float4 a = *(const float4*)&S[e];
  const float4 b = *(const float4*)&S[1048576 + e];
  const int row = e >> 10, col = e & 1023;
  ushort4 o;
  o.x = f2bf(a.x + b.x);
  o.y = f2bf(a.y + b.y);
  o.z = f2bf(a.z + b.z);
  o.w = f2bf(a.w + b.w);
  *(ushort4*)&D[(size_t)row * ld + co + col] = o;
}

// ---------------- gemm_big: 256x256 tile, BK=32, depth-4 LDS, reg dbuf, 1 bar/tile ----------------
// (round-6 proven version, verbatim — ~105 us)
__device__ __forceinline__ void dec_chunk(int s, int& row, int& c) {
  const int r3 = (((s >> 2) ^ (s >> 4)) & 1) | (((s >> 3) & 1) << 1) | (((s >> 4) & 1) << 2);
  const int u = s ^ r3;
  row = u >> 2;
  c = u & 3;
}

__global__ __launch_bounds__(512, 2) void gemm_big(
    const unsigned short* __restrict__ A, const unsigned short* __restrict__ Bt,
    unsigned short* __restrict__ C) {
  constexpr int K = 3072, NT = 96;  // NT = K/32
  __shared__ __align__(16) unsigned short lds[4 * 16384];  // 128 KiB: 4 bufs x [A 16KB | B 16KB]
  const int tid = threadIdx.x;
  const int lane = tid & 63, w = tid >> 6;
  const int wr = w >> 2, wc = w & 3;
  const int lr = lane & 15, lg = lane >> 4;
  const int lin = blockIdx.x;                 // 248 blocks: XCD-bijective swizzle (248 = 8*31)
  const int v = (lin & 7) * 31 + (lin >> 3);
  const int mb = v & 3, nb = v >> 2;
  const int m0 = mb * 256, n0 = nb * 256;

  int r0_, c0_, r1_, c1_;
  dec_chunk((w * 2 + 0) * 64 + lane, r0_, c0_);
  dec_chunk((w * 2 + 1) * 64 + lane, r1_, c1_);
  const unsigned short* sA0 = A + (size_t)(m0 + r0_) * K + c0_ * 8;
  const unsigned short* sA1 = A + (size_t)(m0 + r1_) * K + c1_ * 8;
  const unsigned short* sB0 = Bt + (size_t)(n0 + r0_) * K + c0_ * 8;
  const unsigned short* sB1 = Bt + (size_t)(n0 + r1_) * K + c1_ * 8;
  const int ldsoff0 = (w * 2 + 0) * 512, ldsoff1 = (w * 2 + 1) * 512;

  f32x4 acc[8][4];
  const f32x4 ZV = {0.f, 0.f, 0.f, 0.f};
#pragma unroll
  for (int f = 0; f < 8; ++f)
#pragma unroll
    for (int g = 0; g < 4; ++g) acc[f][g] = ZV;

  const int aoff = (((wr * 128 + lr) * 64 + lg * 16) ^ ((lr & 7) << 4));
  const int boff = (((wc * 64 + lr) * 64 + lg * 16) ^ ((lr & 7) << 4));

  bf16x8 avA[8], bvA[4], avB[8], bvB[4];

#define STAGE(T)                                               \
  do {                                                         \
    unsigned short* ba_ = lds + ((T) & 3) * 16384;             \
    const int k0_ = (T) * 32;                                  \
    gload16(sA0 + k0_, ba_ + ldsoff0);                         \
    gload16(sA1 + k0_, ba_ + ldsoff1);                         \
    gload16(sB0 + k0_, ba_ + 8192 + ldsoff0);                  \
    gload16(sB1 + k0_, ba_ + 8192 + ldsoff1);                  \
  } while (0)

#define DSREAD(T, AN, BN)                                      \
  do {                                                         \
    const char* rb_ = (const char*)lds + ((T) & 3) * 32768;    \
    _Pragma("unroll") for (int f_ = 0; f_ < 8; ++f_)           \
      AN[f_] = *(const bf16x8*)(rb_ + aoff + f_ * 1024);       \
    _Pragma("unroll") for (int g_ = 0; g_ < 4; ++g_)           \
      BN[g_] = *(const bf16x8*)(rb_ + 16384 + boff + g_ * 1024); \
  } while (0)

#define MFMAC(AC, BC)                                          \
  do {                                                         \
    __builtin_amdgcn_s_setprio(1);                             \
    _Pragma("unroll") for (int f_ = 0; f_ < 8; ++f_)           \
      _Pragma("unroll") for (int g_ = 0; g_ < 4; ++g_)         \
        acc[f_][g_] = __builtin_amdgcn_mfma_f32_16x16x32_bf16(AC[f_], BC[g_], acc[f_][g_], 0, 0, 0); \
    __builtin_amdgcn_s_setprio(0);                             \
  } while (0)

  STAGE(0); STAGE(1); STAGE(2); STAGE(3);
  asm volatile("s_waitcnt vmcnt(8)" ::: "memory");
  bar();
  DSREAD(0, avA, bvA);

  for (int tt = 0; tt < NT - 4; tt += 2) {
    DSREAD(tt + 1, avB, bvB);
    STAGE(tt + 4);
    MFMAC(avA, bvA);
    asm volatile("s_waitcnt vmcnt(8) lgkmcnt(0)" ::: "memory");
    bar();
    DSREAD(tt + 2, avA, bvA);
    STAGE(tt + 5);
    MFMAC(avB, bvB);
    asm volatile("s_waitcnt vmcnt(8) lgkmcnt(0)" ::: "memory");
    bar();
  }
  DSREAD(93, avB, bvB);
  MFMAC(avA, bvA);
  asm volatile("s_waitcnt vmcnt(4) lgkmcnt(0)" ::: "memory");
  bar();
  DSREAD(94, avA, bvA);
  MFMAC(avB, bvB);
  asm volatile("s_waitcnt vmcnt(0) lgkmcnt(0)" ::: "memory");
  bar();
  DSREAD(95, avB, bvB);
  MFMAC(avA, bvA);
  asm volatile("s_waitcnt lgkmcnt(0)" ::: "memory");
  __builtin_amdgcn_sched_barrier(0);
  MFMAC(avB, bvB);
#undef STAGE
#undef DSREAD
#undef MFMAC

#pragma unroll
  for (int g = 0; g < 4; ++g) {
    const int n = n0 + wc * 64 + g * 16;
    const size_t jb = (size_t)(n >> 4) * 16384;
#pragma unroll
    for (int f = 0; f < 8; ++f) {
      const int m = m0 + wr * 128 + f * 16 + lg * 4;
#pragma unroll
      for (int i = 0; i < 4; ++i)
        C[jb + (size_t)(m + i) * 16 + lr] = f2bf(fmaxf(acc[f][g][i], 0.f));
    }
  }
}

// ---------------- K1 (v2 + fast sigm + cvt_pk pack): GLU on VALU, Theta on MFMA ----------------
__global__ __launch_bounds__(256) void k1_fused(
    const float* __restrict__ x, const float* __restrict__ W1, const float* __restrict__ b1,
    const float* __restrict__ Theta, unsigned short* __restrict__ Zt) {
  __shared__ __align__(16) unsigned short hs[4 * 64 * 68];  // [w][n][c] pad 68
  __shared__ __align__(16) unsigned short th[3 * 16 * 72];  // [kc][o][c] pad 72
  __shared__ __align__(16) unsigned short tr[64 * 68];      // [row][n] pad 68
  const int tid = threadIdx.x, lane = tid & 63, w = tid >> 6;
  const int n0 = blockIdx.x * 64;
  const int bt0 = blockIdx.y * 4;
  const int bt = bt0 + w;
  const int b = bt / 62, t = bt - b * 62;
  float xv[6];
#pragma unroll
  for (int kt = 0; kt < 3; ++kt) {
    const float2 p = *(const float2*)&x[(size_t)((b * 64 + t + kt) * 1024 + n0 + lane) * 2];
    xv[kt * 2] = p.x;
    xv[kt * 2 + 1] = p.y;
  }
  float h[64];
#pragma unroll
  for (int ch = 0; ch < 64; ++ch) {
    float l = b1[ch], r = b1[64 + ch];
#pragma unroll
    for (int q = 0; q < 6; ++q) {  // uniform indices -> scalar loads
      l += xv[q] * W1[q * 128 + ch];
      r += xv[q] * W1[q * 128 + 64 + ch];
    }
    h[ch] = l * sigm(r);
  }
  // pack h -> hs via v_cvt_pk_bf16_f32 (2 values/inst, RNE — same as f2bf)
#pragma unroll
  for (int c8 = 0; c8 < 8; ++c8) {
    union { unsigned u[4]; uint4 v; } pk;
#pragma unroll
    for (int j = 0; j < 4; ++j)
      pk.u[j] = cvtpk(h[c8 * 8 + 2 * j], h[c8 * 8 + 2 * j + 1]);
    *(uint4*)&hs[(w * 64 + lane) * 68 + c8 * 8] = pk.v;
  }
  for (int idx = tid; idx < 3072; idx += 256) {
    const int kc = idx >> 10, o = (idx >> 6) & 15, c = idx & 63;
    th[kc * 1152 + o * 72 + c] = f2bf(Theta[((kc << 6) | c) * 16 + o]);
  }
  __syncthreads();
  const int lr = lane & 15, lg = lane >> 4;
  const f32x4 ZV = {0.f, 0.f, 0.f, 0.f};
  for (int kc = 0; kc < 3; ++kc) {
    const bf16x8 av0 = *(const bf16x8*)&th[kc * 1152 + lr * 72 + lg * 8];
    const bf16x8 av1 = *(const bf16x8*)&th[kc * 1152 + lr * 72 + 32 + lg * 8];
    f32x4 acc[4];
#pragma unroll
    for (int ns = 0; ns < 4; ++ns) acc[ns] = ZV;
#pragma unroll
    for (int ns = 0; ns < 4; ++ns) {
      const bf16x8 bv0 = *(const bf16x8*)&hs[(w * 64 + ns * 16 + lr) * 68 + lg * 8];
      const bf16x8 bv1 = *(const bf16x8*)&hs[(w * 64 + ns * 16 + lr) * 68 + 32 + lg * 8];
      acc[ns] = __builtin_amdgcn_mfma_f32_16x16x32_bf16(av0, bv0, acc[ns], 0, 0, 0);
      acc[ns] = __builtin_amdgcn_mfma_f32_16x16x32_bf16(av1, bv1, acc[ns], 0, 0, 0);
    }
    if (kc) __syncthreads();
#pragma unroll
    for (int ns = 0; ns < 4; ++ns)
#pragma unroll
      for (int i = 0; i < 4; ++i)
        tr[(w * 16 + lg * 4 + i) * 68 + ns * 16 + lr] = f2bf(acc[ns][i]);
    __syncthreads();
#pragma unroll
    for (int rd = 0; rd < 2; ++rd) {
      const int cidx = rd * 256 + tid;
      const int rl = cidx >> 3, ck = cidx & 7;
      const uint4 v = *(const uint4*)&tr[rl * 68 + ck * 8];
      *(uint4*)&Zt[(size_t)(bt0 * 16 + rl) * 3072 + kc * 1024 + n0 + ck * 8] = v;
    }
  }
}

// ---------------- K3: stage-3 conv+GLU; A-frags direct from global, only W2 in LDS ----------------
__global__ __launch_bounds__(256) void k3_out(
    const unsigned short* __restrict__ accb, const float* __restrict__ W2,
    const float* __restrict__ b2, float* __restrict__ out) {
  __shared__ __align__(16) unsigned short sW[128 * 72];
  const int tid = threadIdx.x, lane = tid & 63, w = tid >> 6;
  const int lr = lane & 15, lg = lane >> 4;
  const int n0 = blockIdx.x * 256;
  const int btp = blockIdx.y;
  const int b = btp / 60, tt = btp - b * 60;
  for (int idx = tid; idx < 2048; idx += 256) {
    const int ch = idx >> 4, k = 48 + (idx & 15);
    sW[ch * 72 + k] = 0;
  }
  for (int idx = tid; idx < 6144; idx += 256) {
    const int k = idx >> 7, ch = idx & 127;
    sW[ch * 72 + k] = f2bf(W2[idx]);
  }
  const int rowb = n0 + w * 64;
  const bf16x8 ZB = {0, 0, 0, 0, 0, 0, 0, 0};
  bf16x8 av[4][2];
#pragma unroll
  for (int f = 0; f < 4; ++f)
#pragma unroll
    for (int hh = 0; hh < 2; ++hh) {
      const int gk = hh * 32 + lg * 8;
      const int kt = gk >> 4, ci = gk & 15;
      av[f][hh] = ZB;
      if (kt < 3)
        av[f][hh] = *(const bf16x8*)&accb[(size_t)(b * 62 + tt + kt) * 16384 +
                                          (size_t)(rowb + f * 16 + lr) * 16 + ci];
    }
  __syncthreads();
  const size_t obase = (size_t)(b * 60 + tt) * 65536;
  const f32x4 ZV = {0.f, 0.f, 0.f, 0.f};
#pragma unroll
  for (int gl = 0; gl < 4; ++gl) {
    const int chl = gl * 16 + lr;
    const bf16x8 bl0 = *(const bf16x8*)&sW[chl * 72 + lg * 8];
    const bf16x8 bl1 = *(const bf16x8*)&sW[chl * 72 + 32 + lg * 8];
    const bf16x8 br0 = *(const bf16x8*)&sW[(64 + chl) * 72 + lg * 8];
    const bf16x8 br1 = *(const bf16x8*)&sW[(64 + chl) * 72 + 32 + lg * 8];
    f32x4 aL[4], aR[4];
#pragma unroll
    for (int f = 0; f < 4; ++f) { aL[f] = ZV; aR[f] = ZV; }
#pragma unroll
    for (int f = 0; f < 4; ++f) {
      aL[f] = __builtin_amdgcn_mfma_f32_16x16x32_bf16(av[f][0], bl0, aL[f], 0, 0, 0);
      aL[f] = __builtin_amdgcn_mfma_f32_16x16x32_bf16(av[f][1], bl1, aL[f], 0, 0, 0);
      aR[f] = __builtin_amdgcn_mfma_f32_16x16x32_bf16(av[f][0], br0, aR[f], 0, 0, 0);
      aR[f] = __builtin_amdgcn_mfma_f32_16x16x32_bf16(av[f][1], br1, aR[f], 0, 0, 0);
    }
    const float bbl = b2[chl], bbr = b2[64 + chl];
#pragma unroll
    for (int f = 0; f < 4; ++f)
#pragma unroll
      for (int i = 0; i < 4; ++i) {
        const float pl = aL[f][i] + bbl;
        const float pr = aR[f][i] + bbr;
        out[obase + (size_t)(rowb + f * 16 + lg * 4 + i) * 64 + chl] = pl * sigm(pr);
      }
  }
}

extern "C" void kernel_launch(void* const* d_in, const int* in_sizes, int n_in,
                              void* d_out, int out_size, void* d_ws, size_t ws_size,
                              hipStream_t stream) {
  const float* x    = (const float*)d_in[0];
  const float* cheb = (const float*)d_in[1];
  const float* W1   = (const float*)d_in[2];
  const float* b1   = (const float*)d_in[3];
  const float* Th   = (const float*)d_in[4];
  const float* W2   = (const float*)d_in[5];
  const float* b2   = (const float*)d_in[6];
  float* out = (float*)d_out;

  char* ws = (char*)d_ws;
  const size_t MB = 1u << 20;
  unsigned short* cb1  = (unsigned short*)(ws);             // 2 MB  cheb1 bf16
  unsigned short* cb2  = (unsigned short*)(ws + 2 * MB);    // 2 MB  cheb2 bf16
  unsigned short* Pbig = (unsigned short*)(ws + 4 * MB);    // 6 MB  (1024 x 3072 bf16)
  unsigned short* t0   = (unsigned short*)(ws + 10 * MB);   // 2 MB  cheb0^T
  unsigned short* t1   = (unsigned short*)(ws + 12 * MB);   // 2 MB  cheb1^T
  unsigned short* Qb   = (unsigned short*)(ws + 14 * MB);   // 2 MB  Q=cheb2@cheb1 (dead before accb)
  unsigned short* accb = (unsigned short*)(ws + 14 * MB);   // 32.5 MB (992 x 1024 x 16), overlaps Qb
  float*          P1f  = (float*)(ws + 48 * MB);            // 8 MB fp32 split partials (P1)
  float*          Qf   = (float*)(ws + 64 * MB);            // 8 MB fp32 split partials (Q)
  float*          P2f  = (float*)(ws + 80 * MB);            // 8 MB fp32 split partials (P2)
  unsigned short* Zt   = (unsigned short*)d_out;            // 97.5 MB scratch in out buf

  k0t<<<dim3(16, 16, 3), 256, 0, stream>>>(cheb, cb1, cb2, Pbig, t0, t1);
  gemm_splitk<<<dim3(64, 2, 2), 256, 0, stream>>>(cb1, t0, P1f, cb2, t1, Qf);
  reducep<<<dim3(1024, 1, 2), 256, 0, stream>>>(P1f, Pbig, 3072, 1024, Qf, Qb, 1024, 0);
  gemm_splitk<<<dim3(64, 2, 1), 256, 0, stream>>>(Qb, t0, P2f, Qb, t0, P2f);
  reducep<<<dim3(1024, 1, 1), 256, 0, stream>>>(P2f, Pbig, 3072, 2048, P2f, Pbig, 3072, 2048);
  k1_fused<<<dim3(16, 248), 256, 0, stream>>>(x, W1, b1, Th, Zt);
  gemm_big<<<dim3(248), dim3(512), 0, stream>>>(Pbig, Zt, accb);
  k3_out<<<dim3(4, 960), 256, 0, stream>>>(accb, W2, b2, out);
}